// Round 6
// baseline (93.672 us; speedup 1.0000x reference)
//
#include <hip/hip_runtime.h>
#include <hip/hip_fp16.h>

// Raymarcher: R=16384 rays, 64 steps, K=32 prims, template (32,4,16,16,16) f32.
// Round 16: r14 base (lane=(prim,parity), fast-path alpha, wave-uniform
// saturation break, DPP reduce, fp16 channel-last template, block=128) with
// EIGHT substeps per iteration: each lane evaluates its prim at substeps
// 8j+parity, +2, +4, +6 -> 4 independent load->lerp chains (16 loads in
// flight) per lane per iteration. Theory: march is latency-bound (exposed L2
// hits, 4 waves/SIMD); r13 showed +ILP is the only lever that moved. Per-
// substep loop/ballot/alpha overhead halves. Exact alpha: fast path identity,
// slow path exact 8-term min-prefix chain (rare).
// r15's cell table reverted (footprint > L2 hurt; line-packing was neutral).

namespace {

constexpr float kDT  = 1.0f / 64.0f;
constexpr int   kVox = 32 * 4096;   // (k,z,y,x) voxel count

struct H4 { __half2 lo, hi; };                                   // one voxel, 8 B
struct __attribute__((aligned(8))) H4x2 { __half2 l0, h0, l1, h1; }; // voxels (x, x+1), 16 B

// ---- pre-pass: (k,c,z,y,x) f32 -> (k,z,y,x,c) fp16 ----
__global__ __launch_bounds__(256) void transpose_tmpl_h(
    const float* __restrict__ tmpl, H4* __restrict__ wsH)
{
    const int idx = blockIdx.x * 256 + threadIdx.x;     // < 131072
    const int k   = idx >> 12;
    const int rem = idx & 4095;
    const float* src = tmpl + k * 16384 + rem;
    H4 v;
    v.lo = __floats2half2_rn(src[0],    src[4096]);
    v.hi = __floats2half2_rn(src[8192], src[12288]);
    wsH[idx] = v;
}

__device__ __forceinline__ __half2 lerp2(__half2 a, __half2 b, __half2 f) {
    return __hfma2(f, __hsub2(b, a), a);
}

template<int CTRL>
__device__ __forceinline__ float dpp_add(float v) {
    return v + __int_as_float(__builtin_amdgcn_update_dpp(
        0, __float_as_int(v), CTRL, 0xF, 0xF, true));
}

// Sum across each 32-lane half; result in every lane of that half.
__device__ __forceinline__ float half_sum32(float v) {
    v = dpp_add<0xB1>(v);    // quad_perm {1,0,3,2}  == lane^1
    v = dpp_add<0x4E>(v);    // quad_perm {2,3,0,1}  == lane^2
    v = dpp_add<0x141>(v);   // row_half_mirror      == lane^4 (groups uniform)
    v = dpp_add<0x140>(v);   // row_mirror           == lane^8 (groups uniform)
    v += __int_as_float(__builtin_amdgcn_ds_swizzle(__float_as_int(v), 0x401F)); // ^16
    return v;
}

__global__ __launch_bounds__(128) void raymarch16(
    const float* __restrict__ raypos,
    const float* __restrict__ raydir,
    const float* __restrict__ tminmax,
    const float* __restrict__ primpos,
    const float* __restrict__ primrot,
    const float* __restrict__ primscale,
    const H4* __restrict__ wsH,
    float* __restrict__ out,
    int R)
{
    const int lane   = threadIdx.x & 63;
    const int wid    = threadIdx.x >> 6;        // wave 0..1
    const int k      = lane & 31;               // prim owned by this lane
    const int parity = lane >> 5;               // substep parity (0 even, 1 odd)
    const int ray    = blockIdx.x * 2 + wid;    // one ray per wave

    const float rpx = raypos[ray * 3 + 0];
    const float rpy = raypos[ray * 3 + 1];
    const float rpz = raypos[ray * 3 + 2];
    const float rdx = raydir[ray * 3 + 0];
    const float rdy = raydir[ray * 3 + 1];
    const float rdz = raydir[ray * 3 + 2];
    const float tmin = tminmax[ray * 2 + 0];
    const float tmax = tminmax[ray * 2 + 1];

    // Fold prim k into affine y_i(t) = A_i + D_i*t (verified r1-r15 math).
    float A0, A1, A2, D0, D1, D2;
    {
        const float ox = rpx - primpos[k * 3 + 0];
        const float oy = rpy - primpos[k * 3 + 1];
        const float oz = rpz - primpos[k * 3 + 2];
        const float s0 = primscale[k * 3 + 0];
        const float s1 = primscale[k * 3 + 1];
        const float s2 = primscale[k * 3 + 2];
        const float* rk = primrot + k * 9;
        A0 = (rk[0] * ox + rk[1] * oy + rk[2] * oz) * s0;
        D0 = (rk[0] * rdx + rk[1] * rdy + rk[2] * rdz) * s0;
        A1 = (rk[3] * ox + rk[4] * oy + rk[5] * oz) * s1;
        D1 = (rk[3] * rdx + rk[4] * rdy + rk[5] * rdz) * s1;
        A2 = (rk[6] * ox + rk[7] * oy + rk[8] * oz) * s2;
        D2 = (rk[6] * rdx + rk[7] * rdy + rk[8] * rdz) * s2;
    }

    const H4* __restrict__ tbase = wsH + k * 4096;

    float alpha = 0.f;                      // wave-uniform
    float r0 = 0.f, r1 = 0.f, r2 = 0.f;     // per-lane rgb partials

    // Per-lane coords for a given substep index (exact r10 arithmetic).
#define COORDS(SUB, IN, AD, FZ, FY, FX)                                  \
    {                                                                    \
        const float tl = fmaf((float)(SUB), kDT, tmin);                  \
        const float y0 = fmaf(D0, tl, A0);                               \
        const float y1 = fmaf(D1, tl, A1);                               \
        const float y2 = fmaf(D2, tl, A2);                               \
        IN = (tl < tmax) && fabsf(y0) <= 1.0f                            \
           && fabsf(y1) <= 1.0f && fabsf(y2) <= 1.0f;                    \
        const float gz = fmaf(y0, 7.5f, 7.5f);                           \
        const float gy = fmaf(y1, 7.5f, 7.5f);                           \
        const float gx = fmaf(y2, 7.5f, 7.5f);                           \
        const int iz = min((int)gz, 14);                                 \
        const int iy = min((int)gy, 14);                                 \
        const int ix = min((int)gx, 14);                                 \
        FZ = fminf(gz - (float)iz, 1.0f);                                \
        FY = fminf(gy - (float)iy, 1.0f);                                \
        FX = fminf(gx - (float)ix, 1.0f);                                \
        AD = iz * 256 + iy * 16 + ix;                                    \
    }

    // Trilinear eval (corner loads + factorized fp16 lerp) -> s0..s3.
#define EVAL(IN, AD, FZ, FY, FX, S0, S1, S2, S3)                         \
    {                                                                    \
        S0 = 0.f; S1 = 0.f; S2 = 0.f; S3 = 0.f;                         \
        if (IN) {                                                        \
            const H4* tp = tbase + (AD);                                 \
            const H4x2 p00 = *(const H4x2*)(tp + 0);                     \
            const H4x2 p01 = *(const H4x2*)(tp + 16);                    \
            const H4x2 p10 = *(const H4x2*)(tp + 256);                   \
            const H4x2 p11 = *(const H4x2*)(tp + 272);                   \
            const __half2 hz = __float2half2_rn(FZ);                     \
            const __half2 hy = __float2half2_rn(FY);                     \
            const __half2 hx = __float2half2_rn(FX);                     \
            const __half2 q0l0 = lerp2(p00.l0, p10.l0, hz);              \
            const __half2 q0h0 = lerp2(p00.h0, p10.h0, hz);              \
            const __half2 q0l1 = lerp2(p00.l1, p10.l1, hz);              \
            const __half2 q0h1 = lerp2(p00.h1, p10.h1, hz);              \
            const __half2 q1l0 = lerp2(p01.l0, p11.l0, hz);              \
            const __half2 q1h0 = lerp2(p01.h0, p11.h0, hz);              \
            const __half2 q1l1 = lerp2(p01.l1, p11.l1, hz);              \
            const __half2 q1h1 = lerp2(p01.h1, p11.h1, hz);              \
            const __half2 ul0 = lerp2(q0l0, q1l0, hy);                   \
            const __half2 uh0 = lerp2(q0h0, q1h0, hy);                   \
            const __half2 ul1 = lerp2(q0l1, q1l1, hy);                   \
            const __half2 uh1 = lerp2(q0h1, q1h1, hy);                   \
            const __half2 vl = lerp2(ul0, ul1, hx);                      \
            const __half2 vh = lerp2(uh0, uh1, hx);                      \
            const float2 fLo = __half22float2(vl);                       \
            const float2 fHi = __half22float2(vh);                       \
            S0 = fLo.x; S1 = fLo.y; S2 = fHi.x; S3 = fHi.y;              \
        }                                                                \
    }

    for (int j = 0; j < 8; ++j) {
        // iteration j covers substeps 8j .. 8j+7; this lane evals its prim at
        // 8j+parity (a), 8j+2+parity (b), 8j+4+parity (c), 8j+6+parity (d).
        bool  inA, inB, inC, inD;
        int   adA, adB, adC, adD;
        float fzA, fyA, fxA, fzB, fyB, fxB, fzC, fyC, fxC, fzD, fyD, fxD;
        COORDS(8 * j + parity,     inA, adA, fzA, fyA, fxA);
        COORDS(8 * j + 2 + parity, inB, adB, fzB, fyB, fxB);
        COORDS(8 * j + 4 + parity, inC, adC, fzC, fyC, fxC);
        COORDS(8 * j + 6 + parity, inD, adD, fzD, fyD, fxD);

        if (__ballot(inA || inB || inC || inD)) {
            float s0a, s1a, s2a, s3a, s0b, s1b, s2b, s3b;
            float s0c, s1c, s2c, s3c, s0d, s1d, s2d, s3d;
            EVAL(inA, adA, fzA, fyA, fxA, s0a, s1a, s2a, s3a);
            EVAL(inB, adB, fzB, fyB, fxB, s0b, s1b, s2b, s3b);
            EVAL(inC, adC, fzC, fyC, fxC, s0c, s1c, s2c, s3c);
            EVAL(inD, adD, fzD, fyD, fxD, s0d, s1d, s2d, s3d);

            // half-local per-slot density totals (each half = one parity).
            const float ta = half_sum32(s3a);
            const float tb = half_sum32(s3b);
            const float tc = half_sum32(s3c);
            const float td = half_sum32(s3d);
            const float sum4 = (ta + tb) + (tc + td);
            const float tot8 = sum4 + __shfl_xor(sum4, 32);  // all 8 substeps
            const float anew = fmaf(tot8, kDT, alpha);

            float ca, cb, cc, cd;
            if (anew < 1.0f) {
                // fast path: clamp inactive anywhere in the 8-substep chain
                // => contrib == inc exactly; half-local, no exchange.
                ca = ta * kDT;
                cb = tb * kDT;
                cc = tc * kDT;
                cd = td * kDT;
                alpha = anew;
            } else {
                // slow path (at most one iteration per ray): exact 8-term
                // min-prefix chain, identical op sequence to the serial ref.
                const float oa = __shfl_xor(ta, 32);
                const float ob = __shfl_xor(tb, 32);
                const float oc = __shfl_xor(tc, 32);
                const float od = __shfl_xor(td, 32);
                const float te0 = parity ? oa : ta;
                const float to0 = parity ? ta : oa;
                const float te1 = parity ? ob : tb;
                const float to1 = parity ? tb : ob;
                const float te2 = parity ? oc : tc;
                const float to2 = parity ? tc : oc;
                const float te3 = parity ? od : td;
                const float to3 = parity ? td : od;
                const float a1 = fminf(fmaf(te0, kDT, alpha), 1.0f);
                const float c0 = a1 - alpha;
                const float a2 = fminf(fmaf(to0, kDT, a1), 1.0f);
                const float c1 = a2 - a1;
                const float a3 = fminf(fmaf(te1, kDT, a2), 1.0f);
                const float c2 = a3 - a2;
                const float a4 = fminf(fmaf(to1, kDT, a3), 1.0f);
                const float c3 = a4 - a3;
                const float a5 = fminf(fmaf(te2, kDT, a4), 1.0f);
                const float c4 = a5 - a4;
                const float a6 = fminf(fmaf(to2, kDT, a5), 1.0f);
                const float c5 = a6 - a5;
                const float a7 = fminf(fmaf(te3, kDT, a6), 1.0f);
                const float c6 = a7 - a6;
                const float a8 = fminf(fmaf(to3, kDT, a7), 1.0f);
                const float c7 = a8 - a7;
                alpha = a8;
                ca = parity ? c1 : c0;
                cb = parity ? c3 : c2;
                cc = parity ? c5 : c4;
                cd = parity ? c7 : c6;
            }

            r0 = fmaf(s0a, ca, fmaf(s0b, cb, fmaf(s0c, cc, fmaf(s0d, cd, r0))));
            r1 = fmaf(s1a, ca, fmaf(s1b, cb, fmaf(s1c, cc, fmaf(s1d, cd, r1))));
            r2 = fmaf(s2a, ca, fmaf(s2b, cb, fmaf(s2c, cc, fmaf(s2d, cd, r2))));
        }

        const float tn = fmaf((float)(8 * j + 8), kDT, tmin);
        if (tn >= tmax || alpha >= 1.0f) break;   // wave-uniform
    }

#undef COORDS
#undef EVAL

    // full-wave rgb reduce (both parity halves contributed)
    r0 = half_sum32(r0); r0 += __shfl_xor(r0, 32);
    r1 = half_sum32(r1); r1 += __shfl_xor(r1, 32);
    r2 = half_sum32(r2); r2 += __shfl_xor(r2, 32);

    if (lane == 0) {
        out[0 * R + ray] = r0;
        out[1 * R + ray] = r1;
        out[2 * R + ray] = r2;
        out[3 * R + ray] = alpha;
        out[4 * R + ray] = r0;
        out[5 * R + ray] = r1;
        out[6 * R + ray] = r2;
        out[7 * R + ray] = alpha;
    }
}

// ---- fallback (r6-style, original f32 template) for tiny ws ----
__global__ __launch_bounds__(256) void raymarch_fb(
    const float* __restrict__ raypos, const float* __restrict__ raydir,
    const float* __restrict__ tminmax, const float* __restrict__ primpos,
    const float* __restrict__ primrot, const float* __restrict__ primscale,
    const float* __restrict__ tmpl, float* __restrict__ out, int R)
{
    const int lane = threadIdx.x & 63;
    const int wid  = threadIdx.x >> 6;
    const int k    = lane & 31;
    const int half = lane >> 5;
    const int ray  = blockIdx.x * 8 + wid * 2 + half;

    const float rpx = raypos[ray*3+0], rpy = raypos[ray*3+1], rpz = raypos[ray*3+2];
    const float rdx = raydir[ray*3+0], rdy = raydir[ray*3+1], rdz = raydir[ray*3+2];
    const float tmin = tminmax[ray*2+0], tmax = tminmax[ray*2+1];

    float A0,A1,A2,D0,D1,D2;
    {
        const float ox = rpx - primpos[k*3+0], oy = rpy - primpos[k*3+1], oz = rpz - primpos[k*3+2];
        const float s0 = primscale[k*3+0], s1 = primscale[k*3+1], s2 = primscale[k*3+2];
        const float* rk = primrot + k*9;
        A0 = (rk[0]*ox+rk[1]*oy+rk[2]*oz)*s0; D0 = (rk[0]*rdx+rk[1]*rdy+rk[2]*rdz)*s0;
        A1 = (rk[3]*ox+rk[4]*oy+rk[5]*oz)*s1; D1 = (rk[3]*rdx+rk[4]*rdy+rk[5]*rdz)*s1;
        A2 = (rk[6]*ox+rk[7]*oy+rk[8]*oz)*s2; D2 = (rk[6]*rdx+rk[7]*rdy+rk[8]*rdz)*s2;
    }
    float alpha = 0.f, r0 = 0.f, r1 = 0.f, r2 = 0.f;
    for (int i = 0; i < 64; ++i) {
        const float t = fmaf((float)i, kDT, tmin);
        const bool live = (t < tmax) && (alpha < 1.0f);
        if (__ballot(live) == 0ull) break;
        const float y0 = fmaf(D0,t,A0), y1 = fmaf(D1,t,A1), y2 = fmaf(D2,t,A2);
        const bool inside = live && fabsf(y0)<=1.f && fabsf(y1)<=1.f && fabsf(y2)<=1.f;
        if (__ballot(inside) == 0ull) continue;
        float s0=0.f,s1=0.f,s2=0.f,s3=0.f;
        if (inside) {
            const float gz=(y0+1.f)*7.5f, gy=(y1+1.f)*7.5f, gx=(y2+1.f)*7.5f;
            const int iz=(int)fminf(floorf(gz),14.f), iy=(int)fminf(floorf(gy),14.f), ix=(int)fminf(floorf(gx),14.f);
            const float fz=fminf(gz-(float)iz,1.f), fy=fminf(gy-(float)iy,1.f), fx=fminf(gx-(float)ix,1.f);
            const float oz_=1.f-fz, oy_=1.f-fy, ox_=1.f-fx;
            const float w000=oz_*oy_*ox_, w001=oz_*oy_*fx, w010=oz_*fy*ox_, w011=oz_*fy*fx;
            const float w100=fz*oy_*ox_, w101=fz*oy_*fx, w110=fz*fy*ox_, w111=fz*fy*fx;
            const float* tp = tmpl + k*16384 + iz*256 + iy*16 + ix;
            float acc[4];
            #pragma unroll
            for (int c = 0; c < 4; ++c) {
                const float* tc = tp + c*4096;
                acc[c] = w000*tc[0]+w001*tc[1]+w010*tc[16]+w011*tc[17]
                       + w100*tc[256]+w101*tc[257]+w110*tc[272]+w111*tc[273];
            }
            s0=acc[0]; s1=acc[1]; s2=acc[2]; s3=acc[3];
        }
        float tot3 = s3;
        #pragma unroll
        for (int m = 1; m < 32; m <<= 1) tot3 += __shfl_xor(tot3, m);
        const float na = fminf(fmaf(tot3, kDT, alpha), 1.0f);
        const float contrib = na - alpha;
        alpha = na;
        r0 = fmaf(s0, contrib, r0); r1 = fmaf(s1, contrib, r1); r2 = fmaf(s2, contrib, r2);
    }
    #pragma unroll
    for (int m = 1; m < 32; m <<= 1) {
        r0 += __shfl_xor(r0, m); r1 += __shfl_xor(r1, m); r2 += __shfl_xor(r2, m);
    }
    if (k == 0) {
        out[0*R+ray]=r0; out[1*R+ray]=r1; out[2*R+ray]=r2; out[3*R+ray]=alpha;
        out[4*R+ray]=r0; out[5*R+ray]=r1; out[6*R+ray]=r2; out[7*R+ray]=alpha;
    }
}

} // namespace

extern "C" void kernel_launch(void* const* d_in, const int* in_sizes, int n_in,
                              void* d_out, int out_size, void* d_ws, size_t ws_size,
                              hipStream_t stream) {
    const float* raypos    = (const float*)d_in[0];
    const float* raydir    = (const float*)d_in[1];
    const float* tminmax   = (const float*)d_in[2];
    const float* primpos   = (const float*)d_in[3];
    const float* primrot   = (const float*)d_in[4];
    const float* primscale = (const float*)d_in[5];
    const float* tmpl      = (const float*)d_in[6];
    float* out = (float*)d_out;

    const int R = in_sizes[0] / 3;   // 16384
    const size_t needH = (size_t)kVox * sizeof(H4);   // 1 MiB

    if (ws_size >= needH) {
        H4* wsH = (H4*)d_ws;
        transpose_tmpl_h<<<dim3(kVox / 256), dim3(256), 0, stream>>>(tmpl, wsH);
        raymarch16<<<dim3(R / 2), dim3(128), 0, stream>>>(
            raypos, raydir, tminmax, primpos, primrot, primscale, wsH, out, R);
    } else {
        raymarch_fb<<<dim3(R / 8), dim3(256), 0, stream>>>(
            raypos, raydir, tminmax, primpos, primrot, primscale, tmpl, out, R);
    }
}

// Round 7
// 86.735 us; speedup vs baseline: 1.0800x; 1.0800x over previous
//
#include <hip/hip_runtime.h>
#include <hip/hip_fp16.h>

// Raymarcher: R=16384 rays, 64 steps, K=32 prims, template (32,4,16,16,16) f32.
// FINAL (r17 = r14 revert, best measured 86.26us): lane=(prim,parity),
// 4 substeps/iter, fast-path alpha (clip inactive => contrib==inc, half-local;
// exact 4-term min-prefix chain only on the rare saturating iteration),
// wave-uniform alpha-saturation break, DPP butterfly reduce, fp16 channel-last
// template, 16B x-pair loads, block=128.
// Ledger: r12 latency surgery ~0, r13 ILPx2 +2.6%, r14 +0.7%, r15 cell-table
// -4%, r16 ILPx4 -8.6%. March is ~issue-bound (~1900 inst x 2cy/wave vs
// ~4050cy wall); dur_us dominated by 41us harness ws-poison fill (83% HBM
// peak) + ~15us launch overhead.

namespace {

constexpr float kDT  = 1.0f / 64.0f;
constexpr int   kVox = 32 * 4096;   // (k,z,y,x) voxel count

struct H4 { __half2 lo, hi; };                                   // one voxel, 8 B
struct __attribute__((aligned(8))) H4x2 { __half2 l0, h0, l1, h1; }; // voxels (x, x+1), 16 B

// ---- pre-pass: (k,c,z,y,x) f32 -> (k,z,y,x,c) fp16 ----
__global__ __launch_bounds__(256) void transpose_tmpl_h(
    const float* __restrict__ tmpl, H4* __restrict__ wsH)
{
    const int idx = blockIdx.x * 256 + threadIdx.x;     // < 131072
    const int k   = idx >> 12;
    const int rem = idx & 4095;
    const float* src = tmpl + k * 16384 + rem;
    H4 v;
    v.lo = __floats2half2_rn(src[0],    src[4096]);
    v.hi = __floats2half2_rn(src[8192], src[12288]);
    wsH[idx] = v;
}

__device__ __forceinline__ __half2 lerp2(__half2 a, __half2 b, __half2 f) {
    return __hfma2(f, __hsub2(b, a), a);
}

template<int CTRL>
__device__ __forceinline__ float dpp_add(float v) {
    return v + __int_as_float(__builtin_amdgcn_update_dpp(
        0, __float_as_int(v), CTRL, 0xF, 0xF, true));
}

// Sum across each 32-lane half; result in every lane of that half.
__device__ __forceinline__ float half_sum32(float v) {
    v = dpp_add<0xB1>(v);    // quad_perm {1,0,3,2}  == lane^1
    v = dpp_add<0x4E>(v);    // quad_perm {2,3,0,1}  == lane^2
    v = dpp_add<0x141>(v);   // row_half_mirror      == lane^4 (groups uniform)
    v = dpp_add<0x140>(v);   // row_mirror           == lane^8 (groups uniform)
    v += __int_as_float(__builtin_amdgcn_ds_swizzle(__float_as_int(v), 0x401F)); // ^16
    return v;
}

__global__ __launch_bounds__(128) void raymarch17(
    const float* __restrict__ raypos,
    const float* __restrict__ raydir,
    const float* __restrict__ tminmax,
    const float* __restrict__ primpos,
    const float* __restrict__ primrot,
    const float* __restrict__ primscale,
    const H4* __restrict__ wsH,
    float* __restrict__ out,
    int R)
{
    const int lane   = threadIdx.x & 63;
    const int wid    = threadIdx.x >> 6;        // wave 0..1
    const int k      = lane & 31;               // prim owned by this lane
    const int parity = lane >> 5;               // substep parity (0 even, 1 odd)
    const int ray    = blockIdx.x * 2 + wid;    // one ray per wave

    const float rpx = raypos[ray * 3 + 0];
    const float rpy = raypos[ray * 3 + 1];
    const float rpz = raypos[ray * 3 + 2];
    const float rdx = raydir[ray * 3 + 0];
    const float rdy = raydir[ray * 3 + 1];
    const float rdz = raydir[ray * 3 + 2];
    const float tmin = tminmax[ray * 2 + 0];
    const float tmax = tminmax[ray * 2 + 1];

    // Fold prim k into affine y_i(t) = A_i + D_i*t (verified r1-r16 math).
    float A0, A1, A2, D0, D1, D2;
    {
        const float ox = rpx - primpos[k * 3 + 0];
        const float oy = rpy - primpos[k * 3 + 1];
        const float oz = rpz - primpos[k * 3 + 2];
        const float s0 = primscale[k * 3 + 0];
        const float s1 = primscale[k * 3 + 1];
        const float s2 = primscale[k * 3 + 2];
        const float* rk = primrot + k * 9;
        A0 = (rk[0] * ox + rk[1] * oy + rk[2] * oz) * s0;
        D0 = (rk[0] * rdx + rk[1] * rdy + rk[2] * rdz) * s0;
        A1 = (rk[3] * ox + rk[4] * oy + rk[5] * oz) * s1;
        D1 = (rk[3] * rdx + rk[4] * rdy + rk[5] * rdz) * s1;
        A2 = (rk[6] * ox + rk[7] * oy + rk[8] * oz) * s2;
        D2 = (rk[6] * rdx + rk[7] * rdy + rk[8] * rdz) * s2;
    }

    const H4* __restrict__ tbase = wsH + k * 4096;

    float alpha = 0.f;                      // wave-uniform
    float r0 = 0.f, r1 = 0.f, r2 = 0.f;     // per-lane rgb partials

    // Per-lane coords for a given substep index (exact r10 arithmetic).
#define COORDS(SUB, IN, AD, FZ, FY, FX)                                  \
    {                                                                    \
        const float tl = fmaf((float)(SUB), kDT, tmin);                  \
        const float y0 = fmaf(D0, tl, A0);                               \
        const float y1 = fmaf(D1, tl, A1);                               \
        const float y2 = fmaf(D2, tl, A2);                               \
        IN = (tl < tmax) && fabsf(y0) <= 1.0f                            \
           && fabsf(y1) <= 1.0f && fabsf(y2) <= 1.0f;                    \
        const float gz = fmaf(y0, 7.5f, 7.5f);                           \
        const float gy = fmaf(y1, 7.5f, 7.5f);                           \
        const float gx = fmaf(y2, 7.5f, 7.5f);                           \
        const int iz = min((int)gz, 14);                                 \
        const int iy = min((int)gy, 14);                                 \
        const int ix = min((int)gx, 14);                                 \
        FZ = fminf(gz - (float)iz, 1.0f);                                \
        FY = fminf(gy - (float)iy, 1.0f);                                \
        FX = fminf(gx - (float)ix, 1.0f);                                \
        AD = iz * 256 + iy * 16 + ix;                                    \
    }

    // Trilinear eval (corner loads + factorized fp16 lerp) -> s0..s3.
#define EVAL(IN, AD, FZ, FY, FX, S0, S1, S2, S3)                         \
    {                                                                    \
        S0 = 0.f; S1 = 0.f; S2 = 0.f; S3 = 0.f;                         \
        if (IN) {                                                        \
            const H4* tp = tbase + (AD);                                 \
            const H4x2 p00 = *(const H4x2*)(tp + 0);                     \
            const H4x2 p01 = *(const H4x2*)(tp + 16);                    \
            const H4x2 p10 = *(const H4x2*)(tp + 256);                   \
            const H4x2 p11 = *(const H4x2*)(tp + 272);                   \
            const __half2 hz = __float2half2_rn(FZ);                     \
            const __half2 hy = __float2half2_rn(FY);                     \
            const __half2 hx = __float2half2_rn(FX);                     \
            const __half2 q0l0 = lerp2(p00.l0, p10.l0, hz);              \
            const __half2 q0h0 = lerp2(p00.h0, p10.h0, hz);              \
            const __half2 q0l1 = lerp2(p00.l1, p10.l1, hz);              \
            const __half2 q0h1 = lerp2(p00.h1, p10.h1, hz);              \
            const __half2 q1l0 = lerp2(p01.l0, p11.l0, hz);              \
            const __half2 q1h0 = lerp2(p01.h0, p11.h0, hz);              \
            const __half2 q1l1 = lerp2(p01.l1, p11.l1, hz);              \
            const __half2 q1h1 = lerp2(p01.h1, p11.h1, hz);              \
            const __half2 ul0 = lerp2(q0l0, q1l0, hy);                   \
            const __half2 uh0 = lerp2(q0h0, q1h0, hy);                   \
            const __half2 ul1 = lerp2(q0l1, q1l1, hy);                   \
            const __half2 uh1 = lerp2(q0h1, q1h1, hy);                   \
            const __half2 vl = lerp2(ul0, ul1, hx);                      \
            const __half2 vh = lerp2(uh0, uh1, hx);                      \
            const float2 fLo = __half22float2(vl);                       \
            const float2 fHi = __half22float2(vh);                       \
            S0 = fLo.x; S1 = fLo.y; S2 = fHi.x; S3 = fHi.y;              \
        }                                                                \
    }

    for (int j = 0; j < 16; ++j) {
        // quad j covers substeps 4j .. 4j+3; this lane evals 4j+parity
        // (slot a) and 4j+2+parity (slot b).
        bool  inA, inB;
        int   adA, adB;
        float fzA, fyA, fxA, fzB, fyB, fxB;
        COORDS(4 * j + parity,     inA, adA, fzA, fyA, fxA);
        COORDS(4 * j + 2 + parity, inB, adB, fzB, fyB, fxB);

        if (__ballot(inA || inB)) {
            float s0a, s1a, s2a, s3a, s0b, s1b, s2b, s3b;
            EVAL(inA, adA, fzA, fyA, fxA, s0a, s1a, s2a, s3a);
            EVAL(inB, adB, fzB, fyB, fxB, s0b, s1b, s2b, s3b);

            // half-local substep totals: ta = my half's slot-a total,
            // tb = my half's slot-b total (halves hold different parities).
            const float ta = half_sum32(s3a);
            const float tb = half_sum32(s3b);
            const float sum2 = ta + tb;
            const float tot4 = sum2 + __shfl_xor(sum2, 32);  // all 4 substeps
            const float anew = fmaf(tot4, kDT, alpha);

            float ca, cb;
            if (anew < 1.0f) {
                // fast path: no clamp active anywhere in the 4-substep chain
                // => contrib_i == inc_i exactly (to fp rounding ~1e-7, vs
                // 0.0625 fp16-template absmax budget). Half-local, no
                // cross-half exchange, no min-chain.
                ca = ta * kDT;
                cb = tb * kDT;
                alpha = anew;
            } else {
                // slow path (at most one iteration per ray): exact 4-term
                // min-prefix chain, identical to r13/r10 semantics.
                const float oa = __shfl_xor(ta, 32);
                const float ob = __shfl_xor(tb, 32);
                const float te0 = parity ? oa : ta;
                const float to0 = parity ? ta : oa;
                const float te1 = parity ? ob : tb;
                const float to1 = parity ? tb : ob;
                const float a1 = fminf(fmaf(te0, kDT, alpha), 1.0f);
                const float c0 = a1 - alpha;
                const float a2 = fminf(fmaf(to0, kDT, a1), 1.0f);
                const float c1 = a2 - a1;
                const float a3 = fminf(fmaf(te1, kDT, a2), 1.0f);
                const float c2 = a3 - a2;
                const float a4 = fminf(fmaf(to1, kDT, a3), 1.0f);
                const float c3 = a4 - a3;
                alpha = a4;
                ca = parity ? c1 : c0;
                cb = parity ? c3 : c2;
            }

            r0 = fmaf(s0a, ca, fmaf(s0b, cb, r0));
            r1 = fmaf(s1a, ca, fmaf(s1b, cb, r1));
            r2 = fmaf(s2a, ca, fmaf(s2b, cb, r2));
        }

        const float tn = fmaf((float)(4 * j + 4), kDT, tmin);
        if (tn >= tmax || alpha >= 1.0f) break;   // wave-uniform
    }

#undef COORDS
#undef EVAL

    // full-wave rgb reduce (both parity halves contributed)
    r0 = half_sum32(r0); r0 += __shfl_xor(r0, 32);
    r1 = half_sum32(r1); r1 += __shfl_xor(r1, 32);
    r2 = half_sum32(r2); r2 += __shfl_xor(r2, 32);

    if (lane == 0) {
        out[0 * R + ray] = r0;
        out[1 * R + ray] = r1;
        out[2 * R + ray] = r2;
        out[3 * R + ray] = alpha;
        out[4 * R + ray] = r0;
        out[5 * R + ray] = r1;
        out[6 * R + ray] = r2;
        out[7 * R + ray] = alpha;
    }
}

// ---- fallback (r6-style, original f32 template) for tiny ws ----
__global__ __launch_bounds__(256) void raymarch_fb(
    const float* __restrict__ raypos, const float* __restrict__ raydir,
    const float* __restrict__ tminmax, const float* __restrict__ primpos,
    const float* __restrict__ primrot, const float* __restrict__ primscale,
    const float* __restrict__ tmpl, float* __restrict__ out, int R)
{
    const int lane = threadIdx.x & 63;
    const int wid  = threadIdx.x >> 6;
    const int k    = lane & 31;
    const int half = lane >> 5;
    const int ray  = blockIdx.x * 8 + wid * 2 + half;

    const float rpx = raypos[ray*3+0], rpy = raypos[ray*3+1], rpz = raypos[ray*3+2];
    const float rdx = raydir[ray*3+0], rdy = raydir[ray*3+1], rdz = raydir[ray*3+2];
    const float tmin = tminmax[ray*2+0], tmax = tminmax[ray*2+1];

    float A0,A1,A2,D0,D1,D2;
    {
        const float ox = rpx - primpos[k*3+0], oy = rpy - primpos[k*3+1], oz = rpz - primpos[k*3+2];
        const float s0 = primscale[k*3+0], s1 = primscale[k*3+1], s2 = primscale[k*3+2];
        const float* rk = primrot + k*9;
        A0 = (rk[0]*ox+rk[1]*oy+rk[2]*oz)*s0; D0 = (rk[0]*rdx+rk[1]*rdy+rk[2]*rdz)*s0;
        A1 = (rk[3]*ox+rk[4]*oy+rk[5]*oz)*s1; D1 = (rk[3]*rdx+rk[4]*rdy+rk[5]*rdz)*s1;
        A2 = (rk[6]*ox+rk[7]*oy+rk[8]*oz)*s2; D2 = (rk[6]*rdx+rk[7]*rdy+rk[8]*rdz)*s2;
    }
    float alpha = 0.f, r0 = 0.f, r1 = 0.f, r2 = 0.f;
    for (int i = 0; i < 64; ++i) {
        const float t = fmaf((float)i, kDT, tmin);
        const bool live = (t < tmax) && (alpha < 1.0f);
        if (__ballot(live) == 0ull) break;
        const float y0 = fmaf(D0,t,A0), y1 = fmaf(D1,t,A1), y2 = fmaf(D2,t,A2);
        const bool inside = live && fabsf(y0)<=1.f && fabsf(y1)<=1.f && fabsf(y2)<=1.f;
        if (__ballot(inside) == 0ull) continue;
        float s0=0.f,s1=0.f,s2=0.f,s3=0.f;
        if (inside) {
            const float gz=(y0+1.f)*7.5f, gy=(y1+1.f)*7.5f, gx=(y2+1.f)*7.5f;
            const int iz=(int)fminf(floorf(gz),14.f), iy=(int)fminf(floorf(gy),14.f), ix=(int)fminf(floorf(gx),14.f);
            const float fz=fminf(gz-(float)iz,1.f), fy=fminf(gy-(float)iy,1.f), fx=fminf(gx-(float)ix,1.f);
            const float oz_=1.f-fz, oy_=1.f-fy, ox_=1.f-fx;
            const float w000=oz_*oy_*ox_, w001=oz_*oy_*fx, w010=oz_*fy*ox_, w011=oz_*fy*fx;
            const float w100=fz*oy_*ox_, w101=fz*oy_*fx, w110=fz*fy*ox_, w111=fz*fy*fx;
            const float* tp = tmpl + k*16384 + iz*256 + iy*16 + ix;
            float acc[4];
            #pragma unroll
            for (int c = 0; c < 4; ++c) {
                const float* tc = tp + c*4096;
                acc[c] = w000*tc[0]+w001*tc[1]+w010*tc[16]+w011*tc[17]
                       + w100*tc[256]+w101*tc[257]+w110*tc[272]+w111*tc[273];
            }
            s0=acc[0]; s1=acc[1]; s2=acc[2]; s3=acc[3];
        }
        float tot3 = s3;
        #pragma unroll
        for (int m = 1; m < 32; m <<= 1) tot3 += __shfl_xor(tot3, m);
        const float na = fminf(fmaf(tot3, kDT, alpha), 1.0f);
        const float contrib = na - alpha;
        alpha = na;
        r0 = fmaf(s0, contrib, r0); r1 = fmaf(s1, contrib, r1); r2 = fmaf(s2, contrib, r2);
    }
    #pragma unroll
    for (int m = 1; m < 32; m <<= 1) {
        r0 += __shfl_xor(r0, m); r1 += __shfl_xor(r1, m); r2 += __shfl_xor(r2, m);
    }
    if (k == 0) {
        out[0*R+ray]=r0; out[1*R+ray]=r1; out[2*R+ray]=r2; out[3*R+ray]=alpha;
        out[4*R+ray]=r0; out[5*R+ray]=r1; out[6*R+ray]=r2; out[7*R+ray]=alpha;
    }
}

} // namespace

extern "C" void kernel_launch(void* const* d_in, const int* in_sizes, int n_in,
                              void* d_out, int out_size, void* d_ws, size_t ws_size,
                              hipStream_t stream) {
    const float* raypos    = (const float*)d_in[0];
    const float* raydir    = (const float*)d_in[1];
    const float* tminmax   = (const float*)d_in[2];
    const float* primpos   = (const float*)d_in[3];
    const float* primrot   = (const float*)d_in[4];
    const float* primscale = (const float*)d_in[5];
    const float* tmpl      = (const float*)d_in[6];
    float* out = (float*)d_out;

    const int R = in_sizes[0] / 3;   // 16384
    const size_t needH = (size_t)kVox * sizeof(H4);   // 1 MiB

    if (ws_size >= needH) {
        H4* wsH = (H4*)d_ws;
        transpose_tmpl_h<<<dim3(kVox / 256), dim3(256), 0, stream>>>(tmpl, wsH);
        raymarch17<<<dim3(R / 2), dim3(128), 0, stream>>>(
            raypos, raydir, tminmax, primpos, primrot, primscale, wsH, out, R);
    } else {
        raymarch_fb<<<dim3(R / 8), dim3(256), 0, stream>>>(
            raypos, raydir, tminmax, primpos, primrot, primscale, tmpl, out, R);
    }
}